// Round 3
// baseline (184.239 us; speedup 1.0000x reference)
//
#include <hip/hip_runtime.h>
#include <hip/hip_fp16.h>

// out[b, i*16+k, h, w] = x[b, i*16+k, h, w]
//   + sum_j ( sum_g rd[g](h,w) * Up(sigmoid(depth))[b, g*256 + i*64 + j*16 + k, h, w] ) * x[b, j*16+k, h, w]
// Up = 2x bilinear (half-pixel, edge-clamped); rd[g] = max(1 - |g - depth_ori*3|, 0)
//
// Wave layout: lane == n (input column); horizontal taps via packed-f16 shuffles
// (__shfl edge behavior == column clamp). b, oc, m are wave-uniform scalars
// (blockIdx + readfirstlane) so all bases live in SGPRs; the only vector
// address component is n*4.

__device__ __forceinline__ float sigmoid_fast(float v) {
    float e = __builtin_amdgcn_exp2f(v * -1.44269504088896340736f);
    return __builtin_amdgcn_rcpf(1.0f + e);
}

__global__ __launch_bounds__(256) void seblock_kernel(
    const float* __restrict__ x,
    const float* __restrict__ depth,
    const float* __restrict__ dori,
    float* __restrict__ out)
{
    const int n    = threadIdx.x & 63;                                  // input col == lane
    const int blk  = blockIdx.x;
    const int msub = __builtin_amdgcn_readfirstlane(threadIdx.x >> 6);  // 0..3, SGPR
    const int m    = ((blk & 15) << 2) | msub;   // scalar input row
    const int oc   = (blk >> 4) & 63;            // scalar
    const int b    = blk >> 10;                  // scalar
    const int i    = oc >> 4;
    const int k    = oc & 15;
    const int h0   = m << 1;

    const int ro0 = (m > 0)  ? -64 : 0;          // clamped row offsets (scalar)
    const int ro2 = (m < 63) ?  64 : 0;

    const float* dbase = depth + (size_t)b * 768 * 4096 + (size_t)m * 64;

    float dva[12], dvb[12];
    auto loadg = [&](float* dst, int g) {
        #pragma unroll
        for (int j = 0; j < 4; ++j) {
            const float* dp = dbase + (size_t)(g * 256 + i * 64 + j * 16 + k) * 4096;
            dst[j * 3 + 0] = dp[n + ro0];
            dst[j * 3 + 1] = dp[n];
            dst[j * 3 + 2] = dp[n + ro2];
        }
    };

    loadg(dva, 0);  // g=0 batch in flight ASAP

    // depth_ori: 2x2 output pixels
    const float* dop = dori + ((size_t)b * 128 + h0) * 128;
    const float2 q0 = *reinterpret_cast<const float2*>(dop + 2 * n);
    const float2 q1 = *reinterpret_cast<const float2*>(dop + 128 + 2 * n);
    const float z0 = q0.x * 3.0f, z1 = q0.y * 3.0f, z2 = q1.x * 3.0f, z3 = q1.y * 3.0f;

    // x: channels j*16+k, 2x2 pixels
    float xs[4][4];
    #pragma unroll
    for (int j = 0; j < 4; ++j) {
        const float* xp = x + (((size_t)b * 64 + (j * 16 + k)) * 128 + h0) * 128;
        const float2 a = *reinterpret_cast<const float2*>(xp + 2 * n);
        const float2 c = *reinterpret_cast<const float2*>(xp + 128 + 2 * n);
        xs[j][0] = a.x; xs[j][1] = a.y; xs[j][2] = c.x; xs[j][3] = c.y;
    }

    float acc[4] = { xs[i][0], xs[i][1], xs[i][2], xs[i][3] };

    const __half2 c25 = __float2half2_rn(0.25f);
    const __half2 c75 = __float2half2_rn(0.75f);

    auto computeg = [&](const float* dv, int g) {
        float dot0 = 0.0f, dot1 = 0.0f, dot2 = 0.0f, dot3 = 0.0f;
        #pragma unroll
        for (int j = 0; j < 4; ++j) {
            const float a0 = sigmoid_fast(dv[j * 3 + 0]);
            const float a1 = sigmoid_fast(dv[j * 3 + 1]);
            const float a2 = sigmoid_fast(dv[j * 3 + 2]);
            // vt = 0.25 a0 + 0.75 a1 (out-row 2m), vb = 0.25 a2 + 0.75 a1 (2m+1), packed
            const __half2 a02 = __floats2half2_rn(a0, a2);
            const __half2 a11 = __float2half2_rn(a1);
            const __half2 vtb = __hfma2(a02, c25, __hmul2(a11, c75));
            const int vi = __builtin_bit_cast(int, vtb);
            const __half2 vtbm = __builtin_bit_cast(__half2, __shfl_up(vi, 1));
            const __half2 vtbp = __builtin_bit_cast(__half2, __shfl_down(vi, 1));
            const __half2 t   = __hmul2(vtb, c75);
            const __half2 u02 = __hfma2(vtbm, c25, t);   // (u @ col 2n:   rows 2m, 2m+1)
            const __half2 u13 = __hfma2(vtbp, c25, t);   // (u @ col 2n+1: rows 2m, 2m+1)
            dot0 = fmaf(__low2float(u02),  xs[j][0], dot0);
            dot1 = fmaf(__low2float(u13),  xs[j][1], dot1);
            dot2 = fmaf(__high2float(u02), xs[j][2], dot2);
            dot3 = fmaf(__high2float(u13), xs[j][3], dot3);
        }
        const float gf = (float)g;
        const float r0 = fmaxf(1.0f - fabsf(gf - z0), 0.0f);
        const float r1 = fmaxf(1.0f - fabsf(gf - z1), 0.0f);
        const float r2 = fmaxf(1.0f - fabsf(gf - z2), 0.0f);
        const float r3 = fmaxf(1.0f - fabsf(gf - z3), 0.0f);
        acc[0] = fmaf(r0, dot0, acc[0]);
        acc[1] = fmaf(r1, dot1, acc[1]);
        acc[2] = fmaf(r2, dot2, acc[2]);
        acc[3] = fmaf(r3, dot3, acc[3]);
    };

    loadg(dvb, 1);      // prefetch g=1
    computeg(dva, 0);
    loadg(dva, 2);      // prefetch g=2
    computeg(dvb, 1);
    computeg(dva, 2);

    float* op = out + (((size_t)b * 64 + oc) * 128 + h0) * 128;
    *reinterpret_cast<float2*>(op + 2 * n)       = make_float2(acc[0], acc[1]);
    *reinterpret_cast<float2*>(op + 128 + 2 * n) = make_float2(acc[2], acc[3]);
}

extern "C" void kernel_launch(void* const* d_in, const int* in_sizes, int n_in,
                              void* d_out, int out_size, void* d_ws, size_t ws_size,
                              hipStream_t stream) {
    const float* x     = (const float*)d_in[0];
    const float* depth = (const float*)d_in[1];
    const float* dori  = (const float*)d_in[2];
    float* out = (float*)d_out;

    // blk = b<<10 | oc<<4 | m0 ; 8 * 64 * 16 = 8192 blocks of 256 threads
    seblock_kernel<<<8192, 256, 0, stream>>>(x, depth, dori, out);
}